// Round 4
// baseline (1255.473 us; speedup 1.0000x reference)
//
#include <hip/hip_runtime.h>
#include <hip/hip_bf16.h>

#define NBATCH 4096
#define NKEYS  64
#define NQRY   27
#define CDIM   384
#define NHEAD  6
#define DHEAD  64

typedef float  f32x4  __attribute__((ext_vector_type(4)));
typedef short  bf16x8 __attribute__((ext_vector_type(8)));

// ---- LDS element offsets (ushort units), phase-overlaid ----
// R0 @0      : sQ [32][392]  (P0-P1)   -> P/L [6][32][64] swizzled (P3a..P5)
// R1 @12544  : sK [64][392]  (P0-P4)   -> x  [32][392]            (P5-P6)
// R2 @37632  : q  [32][392]  (P1-P3a)  -> vt [384][72]            (P4-P5)
// R3 @50176  : kk [64][392]  (P1-P3a)  -> (vt cont.)
#define SQ_E 0
#define P_E  0
#define SK_E 12544
#define X_E  12544
#define Q_E  37632
#define KK_E 50176
#define VT_E 37632
#define RS   392
#define VRS  72
#define LDS_BYTES 150528
#define WS_NEEDED (3u * CDIM * CDIM * 2u)   // 884736 B

__device__ __forceinline__ ushort f2bf(float f) {
  union { float f; unsigned u; } v; v.f = f;
  unsigned u = v.u + 0x7fffu + ((v.u >> 16) & 1u);   // RNE
  return (ushort)(u >> 16);
}
__device__ __forceinline__ float bf2f(ushort s) {
  union { unsigned u; float f; } v; v.u = ((unsigned)s) << 16;
  return v.f;
}

// Weight B-fragment loader.
// WMODE 0: from pre-transposed bf16 wt[n*384+k] (contiguous 16B read).
// WMODE 1: fallback, gather from original f32 W[k*384+n] (stride-C, L2-resident).
template<int WMODE>
__device__ __forceinline__ bf16x8 ldw(const ushort* __restrict__ wt,
                                      const float* __restrict__ wf,
                                      int ncol, int k0) {
  if constexpr (WMODE == 0) {
    return *(const bf16x8*)&wt[ncol * CDIM + k0];
  } else {
    bf16x8 r;
    #pragma unroll
    for (int j = 0; j < 8; ++j) r[j] = (short)f2bf(wf[(k0 + j) * CDIM + ncol]);
    return r;
  }
}

__global__ void prep_weights(const float* __restrict__ Wk,
                             const float* __restrict__ Wv,
                             const float* __restrict__ Wp,
                             ushort* __restrict__ wt) {
  // wt[w][n*384 + k] = W_w[k*384 + n]  (bf16, transposed for contiguous B-frags)
  int t = blockIdx.x * 256 + threadIdx.x;
  if (t >= 3 * CDIM * CDIM) return;
  int w = t / (CDIM * CDIM);
  int r = t % (CDIM * CDIM);
  int k = r / CDIM, n = r % CDIM;          // consecutive t -> consecutive n (coalesced read)
  const float* src = (w == 0) ? Wk : ((w == 1) ? Wv : Wp);
  wt[w * CDIM * CDIM + n * CDIM + k] = f2bf(src[r]);
}

template<int WMODE>
__global__ __launch_bounds__(512, 2) void fused_attn(
    const float* __restrict__ src_k, const float* __restrict__ src_q,
    const ushort* __restrict__ wT,
    const float* __restrict__ Wk_f, const float* __restrict__ Wv_f,
    const float* __restrict__ Wp_f,
    const float* __restrict__ bk, const float* __restrict__ bv,
    const float* __restrict__ pos_bias, const float* __restrict__ bp,
    float* __restrict__ out)
{
  extern __shared__ ushort sm[];
  const int tid  = threadIdx.x;
  const int wid  = tid >> 6;
  const int lane = tid & 63;
  const int l16  = lane & 15;
  const int g4   = lane >> 4;       // 0..3
  const int b    = blockIdx.x;

  const ushort* wkT = wT;
  const ushort* wvT = wT + CDIM * CDIM;
  const ushort* wpT = wT + 2 * CDIM * CDIM;

  // ---------------- P0: stage src_k / src_q as bf16 ----------------
  {
    const float* sk = src_k + (size_t)b * (NKEYS * CDIM);
    #pragma unroll
    for (int i = 0; i < 12; ++i) {                 // 64*96 = 6144 float4
      int idx = tid + i * 512;
      int row = idx / 96, c = idx % 96;
      f32x4 v = *(const f32x4*)(sk + row * CDIM + c * 4);
      ushort4 o;
      o.x = f2bf(v[0]); o.y = f2bf(v[1]); o.z = f2bf(v[2]); o.w = f2bf(v[3]);
      *(ushort4*)&sm[SK_E + row * RS + c * 4] = o;
    }
    const float* sq = src_q + (size_t)b * (NQRY * CDIM);
    #pragma unroll
    for (int i = 0; i < 6; ++i) {                  // 27*96 = 2592 float4
      int idx = tid + i * 512;
      if (idx < 2592) {
        int row = idx / 96, c = idx % 96;
        f32x4 v = *(const f32x4*)(sq + row * CDIM + c * 4);
        ushort4 o;
        o.x = f2bf(v[0]); o.y = f2bf(v[1]); o.z = f2bf(v[2]); o.w = f2bf(v[3]);
        *(ushort4*)&sm[SQ_E + row * RS + c * 4] = o;
      }
    }
    if (tid < 490) {                               // zero pad rows 27..31 of sQ
      int row = 27 + tid / 98, c = tid % 98;
      ushort4 z; z.x = 0; z.y = 0; z.z = 0; z.w = 0;
      *(ushort4*)&sm[SQ_E + row * RS + c * 4] = z;
    }
  }
  __syncthreads();

  // ---------------- P1/2: q = sQ@Wk (+bk)*scale ; k = sK@Wk (+bk) ----------------
  {
    f32x4 accQ[2][3], accK[4][3];
    #pragma unroll
    for (int m = 0; m < 2; ++m)
      #pragma unroll
      for (int n = 0; n < 3; ++n) accQ[m][n] = (f32x4){0.f, 0.f, 0.f, 0.f};
    #pragma unroll
    for (int m = 0; m < 4; ++m)
      #pragma unroll
      for (int n = 0; n < 3; ++n) accK[m][n] = (f32x4){0.f, 0.f, 0.f, 0.f};

    const int n0 = wid * 3;
    for (int ks = 0; ks < 12; ++ks) {
      const int aoff = ks * 32 + g4 * 8;
      bf16x8 aq[2], ak[4], bw[3];
      #pragma unroll
      for (int m = 0; m < 2; ++m) aq[m] = *(const bf16x8*)&sm[SQ_E + (m * 16 + l16) * RS + aoff];
      #pragma unroll
      for (int m = 0; m < 4; ++m) ak[m] = *(const bf16x8*)&sm[SK_E + (m * 16 + l16) * RS + aoff];
      #pragma unroll
      for (int n = 0; n < 3; ++n) bw[n] = ldw<WMODE>(wkT, Wk_f, (n0 + n) * 16 + l16, aoff);
      #pragma unroll
      for (int n = 0; n < 3; ++n) {
        #pragma unroll
        for (int m = 0; m < 2; ++m)
          accQ[m][n] = __builtin_amdgcn_mfma_f32_16x16x32_bf16(aq[m], bw[n], accQ[m][n], 0, 0, 0);
        #pragma unroll
        for (int m = 0; m < 4; ++m)
          accK[m][n] = __builtin_amdgcn_mfma_f32_16x16x32_bf16(ak[m], bw[n], accK[m][n], 0, 0, 0);
      }
    }
    #pragma unroll
    for (int n = 0; n < 3; ++n) {
      const int col = (n0 + n) * 16 + l16;
      const float bkc = bk[col];
      #pragma unroll
      for (int m = 0; m < 2; ++m)
        #pragma unroll
        for (int r = 0; r < 4; ++r) {
          int row = m * 16 + g4 * 4 + r;
          sm[Q_E + row * RS + col] = f2bf((accQ[m][n][r] + bkc) * 0.125f);
        }
      #pragma unroll
      for (int m = 0; m < 4; ++m)
        #pragma unroll
        for (int r = 0; r < 4; ++r) {
          int row = m * 16 + g4 * 4 + r;
          sm[KK_E + row * RS + col] = f2bf(accK[m][n][r] + bkc);
        }
    }
  }
  __syncthreads();

  // ---------------- P3a: logits L[h] = q_h @ k_h^T + pos_bias -> bf16 (swizzled) ----------------
  if (wid < NHEAD) {
    const int h = wid;
    f32x4 accL[2][4];
    #pragma unroll
    for (int m = 0; m < 2; ++m)
      #pragma unroll
      for (int n = 0; n < 4; ++n) accL[m][n] = (f32x4){0.f, 0.f, 0.f, 0.f};
    #pragma unroll
    for (int ks = 0; ks < 2; ++ks) {
      const int koff = h * 64 + ks * 32 + g4 * 8;
      bf16x8 aq[2], bkf[4];
      #pragma unroll
      for (int m = 0; m < 2; ++m) aq[m] = *(const bf16x8*)&sm[Q_E + (m * 16 + l16) * RS + koff];
      #pragma unroll
      for (int n = 0; n < 4; ++n) bkf[n] = *(const bf16x8*)&sm[KK_E + (n * 16 + l16) * RS + koff];
      #pragma unroll
      for (int m = 0; m < 2; ++m)
        #pragma unroll
        for (int n = 0; n < 4; ++n)
          accL[m][n] = __builtin_amdgcn_mfma_f32_16x16x32_bf16(aq[m], bkf[n], accL[m][n], 0, 0, 0);
    }
    #pragma unroll
    for (int m = 0; m < 2; ++m)
      #pragma unroll
      for (int n = 0; n < 4; ++n)
        #pragma unroll
        for (int r = 0; r < 4; ++r) {
          int row = m * 16 + g4 * 4 + r;
          int key = n * 16 + l16;
          float v = accL[m][n][r];
          if (row < NQRY) v += pos_bias[(h * NQRY + row) * 64 + key];
          int e = ((h * 32 + row) * 64 + key) ^ ((row & 7) << 3);
          sm[P_E + e] = f2bf(v);
        }
  }
  __syncthreads();

  // ---------------- P3b: in-place softmax over 64 keys (8 lanes/row) ----------------
  {
    const int c8 = tid & 7;
    const int r0 = tid >> 3;     // 0..63
    #pragma unroll
    for (int p = 0; p < 3; ++p) {
      int r = r0 + p * 64;       // 0..191  (6 heads * 32 rows, pads processed too)
      int h = r >> 5, m = r & 31;
      int base = ((h * 32 + m) * 64 + c8 * 8) ^ ((m & 7) << 3);
      bf16x8 pv = *(const bf16x8*)&sm[P_E + base];
      float f[8];
      #pragma unroll
      for (int j = 0; j < 8; ++j) f[j] = bf2f((ushort)pv[j]);
      float mx = f[0];
      #pragma unroll
      for (int j = 1; j < 8; ++j) mx = fmaxf(mx, f[j]);
      mx = fmaxf(mx, __shfl_xor(mx, 1));
      mx = fmaxf(mx, __shfl_xor(mx, 2));
      mx = fmaxf(mx, __shfl_xor(mx, 4));
      float s = 0.f;
      #pragma unroll
      for (int j = 0; j < 8; ++j) { f[j] = exp2f((f[j] - mx) * 1.44269504f); s += f[j]; }
      s += __shfl_xor(s, 1);
      s += __shfl_xor(s, 2);
      s += __shfl_xor(s, 4);
      float inv = 1.0f / s;
      #pragma unroll
      for (int j = 0; j < 8; ++j) pv[j] = (short)f2bf(f[j] * inv);
      *(bf16x8*)&sm[P_E + base] = pv;
    }
  }
  __syncthreads();

  // ---------------- P4: v = sK@Wv (+bv), stored transposed vt[c][key] ----------------
  {
    f32x4 accV[4][3];
    #pragma unroll
    for (int m = 0; m < 4; ++m)
      #pragma unroll
      for (int n = 0; n < 3; ++n) accV[m][n] = (f32x4){0.f, 0.f, 0.f, 0.f};
    const int n0 = wid * 3;
    for (int ks = 0; ks < 12; ++ks) {
      const int aoff = ks * 32 + g4 * 8;
      bf16x8 ak[4], bw[3];
      #pragma unroll
      for (int m = 0; m < 4; ++m) ak[m] = *(const bf16x8*)&sm[SK_E + (m * 16 + l16) * RS + aoff];
      #pragma unroll
      for (int n = 0; n < 3; ++n) bw[n] = ldw<WMODE>(wvT, Wv_f, (n0 + n) * 16 + l16, aoff);
      #pragma unroll
      for (int n = 0; n < 3; ++n)
        #pragma unroll
        for (int m = 0; m < 4; ++m)
          accV[m][n] = __builtin_amdgcn_mfma_f32_16x16x32_bf16(ak[m], bw[n], accV[m][n], 0, 0, 0);
    }
    #pragma unroll
    for (int n = 0; n < 3; ++n) {
      const int col = (n0 + n) * 16 + l16;      // c index 0..383
      const float bvc = bv[col];
      #pragma unroll
      for (int m = 0; m < 4; ++m)
        #pragma unroll
        for (int r = 0; r < 4; ++r) {
          int key = m * 16 + g4 * 4 + r;
          sm[VT_E + col * VRS + key] = f2bf(accV[m][n][r] + bvc);
        }
    }
  }
  __syncthreads();

  // ---------------- P5: x_h = P_h @ v_h  -> x [32][392] bf16 ----------------
  {
    #pragma unroll
    for (int u3 = 0; u3 < 3; ++u3) {
      const int u = wid * 3 + u3;        // 0..23
      const int h = u >> 2, n = u & 3;
      f32x4 accX[2];
      accX[0] = (f32x4){0.f, 0.f, 0.f, 0.f};
      accX[1] = (f32x4){0.f, 0.f, 0.f, 0.f};
      #pragma unroll
      for (int ks = 0; ks < 2; ++ks) {
        bf16x8 ap[2], bvf;
        #pragma unroll
        for (int m = 0; m < 2; ++m) {
          int row = m * 16 + l16;
          int e = ((h * 32 + row) * 64 + ks * 32 + g4 * 8) ^ ((row & 7) << 3);
          ap[m] = *(const bf16x8*)&sm[P_E + e];
        }
        {
          int c = h * 64 + n * 16 + l16;
          bvf = *(const bf16x8*)&sm[VT_E + c * VRS + ks * 32 + g4 * 8];
        }
        #pragma unroll
        for (int m = 0; m < 2; ++m)
          accX[m] = __builtin_amdgcn_mfma_f32_16x16x32_bf16(ap[m], bvf, accX[m], 0, 0, 0);
      }
      const int col = h * 64 + n * 16 + l16;
      #pragma unroll
      for (int m = 0; m < 2; ++m)
        #pragma unroll
        for (int r = 0; r < 4; ++r) {
          int row = m * 16 + g4 * 4 + r;
          sm[X_E + row * RS + col] = f2bf(accX[m][r]);
        }
    }
  }
  __syncthreads();

  // ---------------- P6: out = x @ Wp + bp  (f32 global store, rows<27) ----------------
  {
    f32x4 accO[2][3];
    #pragma unroll
    for (int m = 0; m < 2; ++m)
      #pragma unroll
      for (int n = 0; n < 3; ++n) accO[m][n] = (f32x4){0.f, 0.f, 0.f, 0.f};
    const int n0 = wid * 3;
    for (int ks = 0; ks < 12; ++ks) {
      const int aoff = ks * 32 + g4 * 8;
      bf16x8 ax[2], bw[3];
      #pragma unroll
      for (int m = 0; m < 2; ++m) ax[m] = *(const bf16x8*)&sm[X_E + (m * 16 + l16) * RS + aoff];
      #pragma unroll
      for (int n = 0; n < 3; ++n) bw[n] = ldw<WMODE>(wpT, Wp_f, (n0 + n) * 16 + l16, aoff);
      #pragma unroll
      for (int n = 0; n < 3; ++n)
        #pragma unroll
        for (int m = 0; m < 2; ++m)
          accO[m][n] = __builtin_amdgcn_mfma_f32_16x16x32_bf16(ax[m], bw[n], accO[m][n], 0, 0, 0);
    }
    float* ob = out + (size_t)b * (NQRY * CDIM);
    #pragma unroll
    for (int n = 0; n < 3; ++n) {
      const int col = (n0 + n) * 16 + l16;
      const float bpc = bp[col];
      #pragma unroll
      for (int m = 0; m < 2; ++m)
        #pragma unroll
        for (int r = 0; r < 4; ++r) {
          int row = m * 16 + g4 * 4 + r;
          if (row < NQRY) ob[row * CDIM + col] = accO[m][n][r] + bpc;
        }
    }
  }
}

extern "C" void kernel_launch(void* const* d_in, const int* in_sizes, int n_in,
                              void* d_out, int out_size, void* d_ws, size_t ws_size,
                              hipStream_t stream) {
  (void)in_sizes; (void)n_in; (void)out_size;
  const float* src_k    = (const float*)d_in[0];
  const float* src_q    = (const float*)d_in[1];
  const float* Wk       = (const float*)d_in[2];
  const float* bk       = (const float*)d_in[3];
  const float* Wv       = (const float*)d_in[4];
  const float* bv       = (const float*)d_in[5];
  const float* pos_bias = (const float*)d_in[6];
  const float* Wp       = (const float*)d_in[7];
  const float* bp       = (const float*)d_in[8];
  float* out = (float*)d_out;

  // Allow >64KB dynamic LDS (no-op / harmless if unsupported).
  (void)hipFuncSetAttribute((const void*)fused_attn<0>,
                            hipFuncAttributeMaxDynamicSharedMemorySize, LDS_BYTES);
  (void)hipFuncSetAttribute((const void*)fused_attn<1>,
                            hipFuncAttributeMaxDynamicSharedMemorySize, LDS_BYTES);

  if (d_ws != nullptr && ws_size >= (size_t)WS_NEEDED) {
    // Fast path: pre-transpose weights to bf16 in workspace.
    ushort* wt = (ushort*)d_ws;    // 3 * 384*384 bf16 = 884736 B
    prep_weights<<<(3 * CDIM * CDIM + 255) / 256, 256, 0, stream>>>(Wk, Wv, Wp, wt);
    fused_attn<0><<<NBATCH, 512, LDS_BYTES, stream>>>(
        src_k, src_q, wt, Wk, Wv, Wp, bk, bv, pos_bias, bp, out);
  } else {
    // Fallback: gather weights from f32 directly (no workspace writes).
    fused_attn<1><<<NBATCH, 512, LDS_BYTES, stream>>>(
        src_k, src_q, (const ushort*)nullptr, Wk, Wv, Wp, bk, bv, pos_bias, bp, out);
  }
}